// Round 1
// baseline (580.448 us; speedup 1.0000x reference)
//
#include <hip/hip_runtime.h>

// SceneSAGE: 3-layer GraphSAGE (mean agg) + ReLU + LayerNorm, fp32.
// N=40000 nodes, E=640000 edges, D: 128 -> 128 -> 64.
//
// Plan:
//   1. Build CSR (deg histogram -> exclusive scan -> scatter col indices).
//   2. Per layer: agg kernel (1 wave per dst node, pure gather, mean),
//      then fused dual-GEMM (+bias +ReLU +LN for layers 0/1) kernel.

#define NN 40000
#define NE 640000
#define DH 128
#define DOUT 64
#define LN_EPS 1e-5f

// ---------------- CSR build ----------------

__global__ void hist_kernel(const int* __restrict__ dst, int* __restrict__ deg) {
    int i = blockIdx.x * blockDim.x + threadIdx.x;
    if (i < NE) atomicAdd(&deg[dst[i]], 1);
}

// per-block inclusive scan of 256 elements; writes offs[i+1], block totals.
__global__ void scan_block(const int* __restrict__ deg, int* __restrict__ offs,
                           int* __restrict__ bsums) {
    __shared__ int s[256];
    int i = blockIdx.x * 256 + threadIdx.x;
    int v = (i < NN) ? deg[i] : 0;
    s[threadIdx.x] = v;
    __syncthreads();
    for (int off = 1; off < 256; off <<= 1) {
        int t = (threadIdx.x >= off) ? s[threadIdx.x - off] : 0;
        __syncthreads();
        s[threadIdx.x] += t;
        __syncthreads();
    }
    if (i < NN) offs[i + 1] = s[threadIdx.x];
    if (threadIdx.x == 255) bsums[blockIdx.x] = s[255];
}

__global__ void scan_sums(int* __restrict__ bsums, int nb) {
    if (blockIdx.x == 0 && threadIdx.x == 0) {
        int acc = 0;
        for (int i = 0; i < nb; ++i) { int v = bsums[i]; bsums[i] = acc; acc += v; }
    }
}

__global__ void add_offs(int* __restrict__ offs, const int* __restrict__ bsums,
                         int* __restrict__ cursor) {
    int i = blockIdx.x * blockDim.x + threadIdx.x;
    if (i == 0) offs[0] = 0;
    if (i < NN) {
        int o = offs[i + 1] + bsums[i >> 8];
        offs[i + 1] = o;
    }
    // cursor[i] = exclusive offset of node i = offs[i]; compute from same data:
    if (i < NN) {
        // offs[i] final value: for i==0 it's 0; else computed by thread i-1 above.
        // To avoid a cross-thread dependency, recompute: cursor filled in a
        // separate kernel below instead.
    }
}

__global__ void fill_cursor(const int* __restrict__ offs, int* __restrict__ cursor) {
    int i = blockIdx.x * blockDim.x + threadIdx.x;
    if (i < NN) cursor[i] = offs[i];
}

__global__ void scatter_edges(const int* __restrict__ src, const int* __restrict__ dst,
                              int* __restrict__ cursor, int* __restrict__ col) {
    int i = blockIdx.x * blockDim.x + threadIdx.x;
    if (i < NE) {
        int p = atomicAdd(&cursor[dst[i]], 1);
        col[p] = src[i];
    }
}

// ---------------- mean aggregation: one wave per node ----------------

__global__ __launch_bounds__(256) void agg_kernel(const float* __restrict__ feat,
                                                  const int* __restrict__ offs,
                                                  const int* __restrict__ col,
                                                  float* __restrict__ meanb) {
    int gid = blockIdx.x * blockDim.x + threadIdx.x;
    int node = gid >> 6;
    int lane = gid & 63;
    if (node >= NN) return;
    int beg = offs[node], end = offs[node + 1];
    float2 s0 = {0.f, 0.f}, s1 = {0.f, 0.f}, s2 = {0.f, 0.f}, s3 = {0.f, 0.f};
    int e = beg;
    for (; e + 3 < end; e += 4) {
        int c0 = col[e], c1 = col[e + 1], c2 = col[e + 2], c3 = col[e + 3];
        float2 v0 = *((const float2*)(feat + (size_t)c0 * DH) + lane);
        float2 v1 = *((const float2*)(feat + (size_t)c1 * DH) + lane);
        float2 v2 = *((const float2*)(feat + (size_t)c2 * DH) + lane);
        float2 v3 = *((const float2*)(feat + (size_t)c3 * DH) + lane);
        s0.x += v0.x; s0.y += v0.y;
        s1.x += v1.x; s1.y += v1.y;
        s2.x += v2.x; s2.y += v2.y;
        s3.x += v3.x; s3.y += v3.y;
    }
    for (; e < end; ++e) {
        int c = col[e];
        float2 v = *((const float2*)(feat + (size_t)c * DH) + lane);
        s0.x += v.x; s0.y += v.y;
    }
    float sx = (s0.x + s1.x) + (s2.x + s3.x);
    float sy = (s0.y + s1.y) + (s2.y + s3.y);
    float inv = 1.0f / fmaxf((float)(end - beg), 1.0f);
    float2 r; r.x = sx * inv; r.y = sy * inv;
    *((float2*)(meanb + (size_t)node * DH) + lane) = r;
}

// ---------------- fused dual-GEMM (+bias [+ReLU+LN]) ----------------
// out[i,:] = mean[i,:] @ Wl + bl + self[i,:] @ Wr   (then optional relu+LN)
// 64 rows per block, 256 threads. K = DH = 128 always. DC = output cols.

template <int DC, bool LNRELU>
__global__ __launch_bounds__(256) void gemm_kernel(
    const float* __restrict__ Amean, const float* __restrict__ Aself,
    const float* __restrict__ Wl, const float* __restrict__ bl,
    const float* __restrict__ Wr,
    const float* __restrict__ g, const float* __restrict__ bln,
    float* __restrict__ out) {
    constexpr int RG = 256 / DC;   // row groups (2 for DC=128, 4 for DC=64)
    constexpr int RPT = 64 / RG;   // rows per thread (32 / 16)
    __shared__ float Am[64][DH];
    __shared__ float Ax[64][DH];
    __shared__ float mu_s[64], rs_s[64];

    const int tid = threadIdx.x;
    const int row0 = blockIdx.x * 64;

    // stage 64x128 tiles of mean and self features
    {
        const float4* gm = (const float4*)(Amean + (size_t)row0 * DH);
        const float4* gx = (const float4*)(Aself + (size_t)row0 * DH);
        float4* lm = (float4*)&Am[0][0];
        float4* lx = (float4*)&Ax[0][0];
#pragma unroll
        for (int i = 0; i < 8; ++i) {
            lm[tid + i * 256] = gm[tid + i * 256];
            lx[tid + i * 256] = gx[tid + i * 256];
        }
    }
    __syncthreads();

    const int tx = tid % DC;
    const int ty = tid / DC;
    float acc[RPT];
#pragma unroll
    for (int r = 0; r < RPT; ++r) acc[r] = 0.f;

    for (int k = 0; k < DH; k += 4) {
        float wl0 = Wl[(k + 0) * DC + tx];
        float wl1 = Wl[(k + 1) * DC + tx];
        float wl2 = Wl[(k + 2) * DC + tx];
        float wl3 = Wl[(k + 3) * DC + tx];
        float wr0 = Wr[(k + 0) * DC + tx];
        float wr1 = Wr[(k + 1) * DC + tx];
        float wr2 = Wr[(k + 2) * DC + tx];
        float wr3 = Wr[(k + 3) * DC + tx];
#pragma unroll
        for (int r = 0; r < RPT; ++r) {
            int row = ty * RPT + r;
            float4 am = *(const float4*)&Am[row][k];
            float4 ax = *(const float4*)&Ax[row][k];
            acc[r] += am.x * wl0 + am.y * wl1 + am.z * wl2 + am.w * wl3;
            acc[r] += ax.x * wr0 + ax.y * wr1 + ax.z * wr2 + ax.w * wr3;
        }
    }

    const float bias = bl[tx];
    if (!LNRELU) {
#pragma unroll
        for (int r = 0; r < RPT; ++r) {
            int row = ty * RPT + r;
            out[(size_t)(row0 + row) * DC + tx] = acc[r] + bias;
        }
    } else {
        __syncthreads();  // everyone done reading Am before overwrite
#pragma unroll
        for (int r = 0; r < RPT; ++r) {
            int row = ty * RPT + r;
            Am[row][tx] = fmaxf(acc[r] + bias, 0.f);
        }
        __syncthreads();
        // LN stats: 4 waves, 16 rows each, 2 elems/lane + wave shuffle reduce
        int wave = tid >> 6, lane = tid & 63;
        for (int rr = 0; rr < 16; ++rr) {
            int row = wave * 16 + rr;
            float a = Am[row][lane];
            float b = Am[row][lane + 64];
            float s = a + b;
            float q = a * a + b * b;
#pragma unroll
            for (int off = 32; off > 0; off >>= 1) {
                s += __shfl_down(s, off, 64);
                q += __shfl_down(q, off, 64);
            }
            if (lane == 0) {
                float mu = s * (1.f / 128.f);
                float var = q * (1.f / 128.f) - mu * mu;
                mu_s[row] = mu;
                rs_s[row] = rsqrtf(var + LN_EPS);
            }
        }
        __syncthreads();
        float gg = g[tx], bb = bln[tx];
#pragma unroll
        for (int r = 0; r < RPT; ++r) {
            int row = ty * RPT + r;
            float v = (Am[row][tx] - mu_s[row]) * rs_s[row];
            out[(size_t)(row0 + row) * DC + tx] = v * gg + bb;
        }
    }
}

// ---------------- launch ----------------

static inline size_t alignup(size_t x) { return (x + 1023) & ~(size_t)1023; }

extern "C" void kernel_launch(void* const* d_in, const int* in_sizes, int n_in,
                              void* d_out, int out_size, void* d_ws, size_t ws_size,
                              hipStream_t stream) {
    const float* x   = (const float*)d_in[0];
    const int* ei    = (const int*)d_in[1];
    const float* Wl0 = (const float*)d_in[2];
    const float* bl0 = (const float*)d_in[3];
    const float* Wr0 = (const float*)d_in[4];
    const float* Wl1 = (const float*)d_in[5];
    const float* bl1 = (const float*)d_in[6];
    const float* Wr1 = (const float*)d_in[7];
    const float* Wl2 = (const float*)d_in[8];
    const float* bl2 = (const float*)d_in[9];
    const float* Wr2 = (const float*)d_in[10];
    const float* g0  = (const float*)d_in[11];
    const float* b0  = (const float*)d_in[12];
    const float* g1  = (const float*)d_in[13];
    const float* b1  = (const float*)d_in[14];

    const int* src = ei;
    const int* dst = ei + NE;

    char* p = (char*)d_ws;
    int* deg    = (int*)p; p += alignup((size_t)NN * 4);
    int* offs   = (int*)p; p += alignup((size_t)(NN + 1) * 4);
    int* bsums  = (int*)p; p += alignup(256 * 4);
    int* cursor = (int*)p; p += alignup((size_t)NN * 4);
    int* col    = (int*)p; p += alignup((size_t)NE * 4);
    float* meanb = (float*)p; p += alignup((size_t)NN * DH * 4);
    float* h0    = (float*)p; p += alignup((size_t)NN * DH * 4);
    float* h1    = (float*)p; p += alignup((size_t)NN * DH * 4);
    float* outf  = (float*)d_out;

    const int nbScan = (NN + 255) / 256;  // 157

    // ---- CSR build ----
    hipMemsetAsync(deg, 0, (size_t)NN * 4, stream);
    hist_kernel<<<(NE + 255) / 256, 256, 0, stream>>>(dst, deg);
    scan_block<<<nbScan, 256, 0, stream>>>(deg, offs, bsums);
    scan_sums<<<1, 64, 0, stream>>>(bsums, nbScan);
    add_offs<<<nbScan, 256, 0, stream>>>(offs, bsums, cursor);
    fill_cursor<<<nbScan, 256, 0, stream>>>(offs, cursor);
    scatter_edges<<<(NE + 255) / 256, 256, 0, stream>>>(src, dst, cursor, col);

    const int aggBlocks = (NN * 64 + 255) / 256;  // 10000
    const int gemmBlocks = NN / 64;               // 625

    // ---- layer 0 ----
    agg_kernel<<<aggBlocks, 256, 0, stream>>>(x, offs, col, meanb);
    gemm_kernel<128, true><<<gemmBlocks, 256, 0, stream>>>(
        meanb, x, Wl0, bl0, Wr0, g0, b0, h0);

    // ---- layer 1 ----
    agg_kernel<<<aggBlocks, 256, 0, stream>>>(h0, offs, col, meanb);
    gemm_kernel<128, true><<<gemmBlocks, 256, 0, stream>>>(
        meanb, h0, Wl1, bl1, Wr1, g1, b1, h1);

    // ---- layer 2 (no relu/LN, D_OUT=64) ----
    agg_kernel<<<aggBlocks, 256, 0, stream>>>(h1, offs, col, meanb);
    gemm_kernel<64, false><<<gemmBlocks, 256, 0, stream>>>(
        meanb, h1, Wl2, bl2, Wr2, nullptr, nullptr, outf);
}

// Round 2
// 332.447 us; speedup vs baseline: 1.7460x; 1.7460x over previous
//
#include <hip/hip_runtime.h>

// SceneSAGE: 3-layer GraphSAGE (mean agg) + ReLU + LayerNorm.
// N=40000 nodes, E=640000 edges, D: 128 -> 128 -> 64.
//
// Round 2: bf16 MFMA GEMMs (16x16x32), LDS-free fragment loads,
// bf16 activation storage [mean|self] per row, bf16 gather aggregation.

#define NN 40000
#define NE 640000
#define DH 128
#define LN_EPS 1e-5f

typedef __attribute__((ext_vector_type(8))) short short8;
typedef __attribute__((ext_vector_type(4))) float float4v;

__device__ __forceinline__ unsigned short f2b(float f) {
    unsigned int u = __float_as_uint(f);
    unsigned int r = (u + 0x7fffu + ((u >> 16) & 1u)) >> 16;
    return (unsigned short)r;
}
__device__ __forceinline__ float b2f(unsigned short b) {
    return __uint_as_float(((unsigned int)b) << 16);
}

// ---------------- CSR build ----------------

__global__ void hist_kernel(const int* __restrict__ dst, int* __restrict__ deg) {
    int i = blockIdx.x * blockDim.x + threadIdx.x;
    if (i < NE) atomicAdd(&deg[dst[i]], 1);
}

__global__ void scan_block(const int* __restrict__ deg, int* __restrict__ offs,
                           int* __restrict__ bsums) {
    __shared__ int s[256];
    int i = blockIdx.x * 256 + threadIdx.x;
    int v = (i < NN) ? deg[i] : 0;
    s[threadIdx.x] = v;
    __syncthreads();
    for (int off = 1; off < 256; off <<= 1) {
        int t = (threadIdx.x >= off) ? s[threadIdx.x - off] : 0;
        __syncthreads();
        s[threadIdx.x] += t;
        __syncthreads();
    }
    if (i < NN) offs[i + 1] = s[threadIdx.x];
    if (threadIdx.x == 255) bsums[blockIdx.x] = s[255];
}

__global__ void scan_sums(int* __restrict__ bsums, int nb) {
    if (blockIdx.x == 0 && threadIdx.x == 0) {
        int acc = 0;
        for (int i = 0; i < nb; ++i) { int v = bsums[i]; bsums[i] = acc; acc += v; }
    }
}

__global__ void add_offs(int* __restrict__ offs, const int* __restrict__ bsums) {
    int i = blockIdx.x * blockDim.x + threadIdx.x;
    if (i == 0) offs[0] = 0;
    if (i < NN) offs[i + 1] += bsums[i >> 8];
}

__global__ void fill_cursor(const int* __restrict__ offs, int* __restrict__ cursor) {
    int i = blockIdx.x * blockDim.x + threadIdx.x;
    if (i < NN) cursor[i] = offs[i];
}

__global__ void scatter_edges(const int* __restrict__ src, const int* __restrict__ dst,
                              int* __restrict__ cursor, int* __restrict__ col) {
    int i = blockIdx.x * blockDim.x + threadIdx.x;
    if (i < NE) {
        int p = atomicAdd(&cursor[dst[i]], 1);
        col[p] = src[i];
    }
}

// ---------------- fp32 x -> bf16 self-columns of hcat ----------------
// hcat row layout: [mean 128 | self 128] bf16, stride 256.

__global__ __launch_bounds__(256) void convert_x(const float* __restrict__ x,
                                                 unsigned short* __restrict__ h) {
    int i = blockIdx.x * blockDim.x + threadIdx.x;   // handles 4 floats
    int idx = i * 4;
    if (idx >= NN * DH) return;
    int m = idx >> 7, j = idx & 127;
    float4 v = *(const float4*)(x + idx);
    unsigned int lo = (unsigned int)f2b(v.x) | ((unsigned int)f2b(v.y) << 16);
    unsigned int hi = (unsigned int)f2b(v.z) | ((unsigned int)f2b(v.w) << 16);
    unsigned int* p = (unsigned int*)(h + (size_t)m * 256 + 128 + j);
    p[0] = lo; p[1] = hi;
}

// ---------------- weight packing into B-fragment order ----------------
// Bp[ks][n][kk] = Wcat[ks*32+kk][n], Wcat = [Wl ; Wr] (256 x DC), bf16.

template <int DC>
__global__ __launch_bounds__(256) void pack_w(const float* __restrict__ Wl,
                                              const float* __restrict__ Wr,
                                              unsigned short* __restrict__ Bp) {
    int tid = blockIdx.x * blockDim.x + threadIdx.x;
    if (tid >= 256 * DC) return;
    int k = tid / DC, n = tid % DC;
    float v = (k < 128) ? Wl[k * DC + n] : Wr[(k - 128) * DC + n];
    int ks = k >> 5, kk = k & 31;
    Bp[((size_t)ks * DC + n) * 32 + kk] = f2b(v);
}

// ---------------- mean aggregation (bf16 rows): one wave per node -------
// reads self cols of hin, writes mean cols of hout (same buffer).

__global__ __launch_bounds__(256) void agg_bf16(const unsigned short* __restrict__ h,
                                                const int* __restrict__ offs,
                                                const int* __restrict__ col,
                                                unsigned short* __restrict__ hm) {
    int gid = blockIdx.x * blockDim.x + threadIdx.x;
    int node = gid >> 6;
    int lane = gid & 63;
    if (node >= NN) return;
    int beg = offs[node], end = offs[node + 1];
    const unsigned short* base = h + 128 + lane * 2;
    float s0x = 0.f, s0y = 0.f, s1x = 0.f, s1y = 0.f;
    float s2x = 0.f, s2y = 0.f, s3x = 0.f, s3y = 0.f;
    int e = beg;
    for (; e + 3 < end; e += 4) {
        int c0 = col[e], c1 = col[e + 1], c2 = col[e + 2], c3 = col[e + 3];
        unsigned int v0 = *(const unsigned int*)(base + (size_t)c0 * 256);
        unsigned int v1 = *(const unsigned int*)(base + (size_t)c1 * 256);
        unsigned int v2 = *(const unsigned int*)(base + (size_t)c2 * 256);
        unsigned int v3 = *(const unsigned int*)(base + (size_t)c3 * 256);
        s0x += __uint_as_float(v0 << 16); s0y += __uint_as_float(v0 & 0xffff0000u);
        s1x += __uint_as_float(v1 << 16); s1y += __uint_as_float(v1 & 0xffff0000u);
        s2x += __uint_as_float(v2 << 16); s2y += __uint_as_float(v2 & 0xffff0000u);
        s3x += __uint_as_float(v3 << 16); s3y += __uint_as_float(v3 & 0xffff0000u);
    }
    for (; e < end; ++e) {
        int c = col[e];
        unsigned int v = *(const unsigned int*)(base + (size_t)c * 256);
        s0x += __uint_as_float(v << 16); s0y += __uint_as_float(v & 0xffff0000u);
    }
    float sx = (s0x + s1x) + (s2x + s3x);
    float sy = (s0y + s1y) + (s2y + s3y);
    float inv = 1.0f / fmaxf((float)(end - beg), 1.0f);
    unsigned int o = (unsigned int)f2b(sx * inv) | ((unsigned int)f2b(sy * inv) << 16);
    *(unsigned int*)(hm + (size_t)node * 256 + lane * 2) = o;
}

// ---------------- MFMA dual-GEMM (+bias [+ReLU+LN]) ----------------
// A: hcat rows (bf16, stride 256, K=256). B: packed Bp. Out DC cols.
// Block = 256 threads = 4 waves; wave handles 32 rows (2 M-tiles of 16).
// K loop: 8 steps of 32. N: DC/16 tiles of 16.

template <int DC, bool LNRELU>
__global__ __launch_bounds__(256) void gemm_mfma(
    const unsigned short* __restrict__ A,
    const unsigned short* __restrict__ Bp,
    const float* __restrict__ bl,
    const float* __restrict__ g, const float* __restrict__ bln,
    unsigned short* __restrict__ outb,   // next hcat (self cols), LNRELU
    float* __restrict__ outf) {          // final fp32 out, !LNRELU
    constexpr int NT = DC / 16;
    const int tid = threadIdx.x;
    const int wave = tid >> 6, lane = tid & 63;
    const int quad = lane >> 4, l16 = lane & 15;
    const long row0 = (long)blockIdx.x * 128 + wave * 32;
    if (row0 >= NN) return;

    float4v acc[2][NT];
#pragma unroll
    for (int m = 0; m < 2; ++m)
#pragma unroll
        for (int nt = 0; nt < NT; ++nt)
#pragma unroll
            for (int r = 0; r < 4; ++r) acc[m][nt][r] = 0.f;

    const unsigned short* a0p = A + (row0 + l16) * 256 + quad * 8;
    const unsigned short* a1p = a0p + 16 * 256;

#pragma unroll
    for (int ks = 0; ks < 8; ++ks) {
        short8 a0 = *(const short8*)(a0p + ks * 32);
        short8 a1 = *(const short8*)(a1p + ks * 32);
        const unsigned short* bp = Bp + ((size_t)ks * DC + l16) * 32 + quad * 8;
#pragma unroll
        for (int nt = 0; nt < NT; ++nt) {
            short8 b = *(const short8*)(bp + nt * 16 * 32);
            acc[0][nt] = __builtin_amdgcn_mfma_f32_16x16x32_bf16(a0, b, acc[0][nt], 0, 0, 0);
            acc[1][nt] = __builtin_amdgcn_mfma_f32_16x16x32_bf16(a1, b, acc[1][nt], 0, 0, 0);
        }
    }

    float bias[NT];
#pragma unroll
    for (int nt = 0; nt < NT; ++nt) bias[nt] = bl[nt * 16 + l16];

    if (!LNRELU) {
#pragma unroll
        for (int m = 0; m < 2; ++m)
#pragma unroll
            for (int r = 0; r < 4; ++r) {
                long row = row0 + m * 16 + quad * 4 + r;
#pragma unroll
                for (int nt = 0; nt < NT; ++nt)
                    outf[row * DC + nt * 16 + l16] = acc[m][nt][r] + bias[nt];
            }
    } else {
        float gv[NT], bv[NT];
#pragma unroll
        for (int nt = 0; nt < NT; ++nt) { gv[nt] = g[nt * 16 + l16]; bv[nt] = bln[nt * 16 + l16]; }
#pragma unroll
        for (int m = 0; m < 2; ++m) {
#pragma unroll
            for (int r = 0; r < 4; ++r) {
                float v[NT];
                float s = 0.f, q = 0.f;
#pragma unroll
                for (int nt = 0; nt < NT; ++nt) {
                    float t = fmaxf(acc[m][nt][r] + bias[nt], 0.f);
                    v[nt] = t; s += t; q += t * t;
                }
                // reduce across the 16 lanes of this quad (row owners)
#pragma unroll
                for (int mask = 1; mask < 16; mask <<= 1) {
                    s += __shfl_xor(s, mask, 64);
                    q += __shfl_xor(q, mask, 64);
                }
                float mu = s * (1.f / 128.f);
                float rstd = rsqrtf(q * (1.f / 128.f) - mu * mu + LN_EPS);
                long row = row0 + m * 16 + quad * 4 + r;
                unsigned short* op = outb + row * 256 + 128 + l16;
#pragma unroll
                for (int nt = 0; nt < NT; ++nt)
                    op[nt * 16] = f2b((v[nt] - mu) * rstd * gv[nt] + bv[nt]);
            }
        }
    }
}

// ---------------- launch ----------------

static inline size_t alignup(size_t x) { return (x + 1023) & ~(size_t)1023; }

extern "C" void kernel_launch(void* const* d_in, const int* in_sizes, int n_in,
                              void* d_out, int out_size, void* d_ws, size_t ws_size,
                              hipStream_t stream) {
    const float* x   = (const float*)d_in[0];
    const int* ei    = (const int*)d_in[1];
    const float* Wl0 = (const float*)d_in[2];
    const float* bl0 = (const float*)d_in[3];
    const float* Wr0 = (const float*)d_in[4];
    const float* Wl1 = (const float*)d_in[5];
    const float* bl1 = (const float*)d_in[6];
    const float* Wr1 = (const float*)d_in[7];
    const float* Wl2 = (const float*)d_in[8];
    const float* bl2 = (const float*)d_in[9];
    const float* Wr2 = (const float*)d_in[10];
    const float* g0  = (const float*)d_in[11];
    const float* b0  = (const float*)d_in[12];
    const float* g1  = (const float*)d_in[13];
    const float* b1  = (const float*)d_in[14];

    const int* src = ei;
    const int* dst = ei + NE;

    char* p = (char*)d_ws;
    int* deg    = (int*)p; p += alignup((size_t)NN * 4);
    int* offs   = (int*)p; p += alignup((size_t)(NN + 1) * 4);
    int* bsums  = (int*)p; p += alignup(256 * 4);
    int* col    = (int*)p; p += alignup((size_t)NE * 4);
    unsigned short* hA = (unsigned short*)p; p += alignup((size_t)NN * 256 * 2);
    unsigned short* hB = (unsigned short*)p; p += alignup((size_t)NN * 256 * 2);
    unsigned short* W0p = (unsigned short*)p; p += alignup((size_t)256 * 128 * 2);
    unsigned short* W1p = (unsigned short*)p; p += alignup((size_t)256 * 128 * 2);
    unsigned short* W2p = (unsigned short*)p; p += alignup((size_t)256 * 64 * 2);
    int* cursor = deg;  // deg dead after scan_block
    float* outf = (float*)d_out;

    const int nbScan = (NN + 255) / 256;

    // ---- CSR build ----
    hipMemsetAsync(deg, 0, (size_t)NN * 4, stream);
    hist_kernel<<<(NE + 255) / 256, 256, 0, stream>>>(dst, deg);
    scan_block<<<nbScan, 256, 0, stream>>>(deg, offs, bsums);
    scan_sums<<<1, 64, 0, stream>>>(bsums, nbScan);
    add_offs<<<nbScan, 256, 0, stream>>>(offs, bsums);
    fill_cursor<<<nbScan, 256, 0, stream>>>(offs, cursor);
    scatter_edges<<<(NE + 255) / 256, 256, 0, stream>>>(src, dst, cursor, col);

    // ---- weight packing + x conversion ----
    pack_w<128><<<128, 256, 0, stream>>>(Wl0, Wr0, W0p);
    pack_w<128><<<128, 256, 0, stream>>>(Wl1, Wr1, W1p);
    pack_w<64><<<64, 256, 0, stream>>>(Wl2, Wr2, W2p);
    convert_x<<<(NN * DH / 4 + 255) / 256, 256, 0, stream>>>(x, hA);

    const int aggBlocks = (NN * 64 + 255) / 256;   // 10000
    const int gemmBlocks = (NN + 127) / 128;       // 313

    // ---- layer 0: hA = [agg(x)|x] -> hB self ----
    agg_bf16<<<aggBlocks, 256, 0, stream>>>(hA, offs, col, hA);
    gemm_mfma<128, true><<<gemmBlocks, 256, 0, stream>>>(
        hA, W0p, bl0, g0, b0, hB, nullptr);

    // ---- layer 1: hB -> hA self ----
    agg_bf16<<<aggBlocks, 256, 0, stream>>>(hB, offs, col, hB);
    gemm_mfma<128, true><<<gemmBlocks, 256, 0, stream>>>(
        hB, W1p, bl1, g1, b1, hA, nullptr);

    // ---- layer 2: hA -> d_out (fp32, 64 cols) ----
    agg_bf16<<<aggBlocks, 256, 0, stream>>>(hA, offs, col, hA);
    gemm_mfma<64, false><<<gemmBlocks, 256, 0, stream>>>(
        hA, W2p, bl2, nullptr, nullptr, nullptr, outf);
}

// Round 3
// 320.294 us; speedup vs baseline: 1.8122x; 1.0379x over previous
//
#include <hip/hip_runtime.h>

// SceneSAGE: 3-layer GraphSAGE (mean agg) + ReLU + LayerNorm.
// N=40000 nodes, E=640000 edges, D: 128 -> 128 -> 64.
//
// Round 3: 16 rows/wave GEMM (2500 waves, was 1252) for latency hiding;
// exact 625x64 grid (fixes round-2 OOB race past hB); merged CSR kernels;
// 8-deep agg unroll.

#define NN 40000
#define NE 640000
#define DH 128
#define LN_EPS 1e-5f

typedef __attribute__((ext_vector_type(8))) short short8;
typedef __attribute__((ext_vector_type(4))) float float4v;

__device__ __forceinline__ unsigned short f2b(float f) {
    unsigned int u = __float_as_uint(f);
    unsigned int r = (u + 0x7fffu + ((u >> 16) & 1u)) >> 16;
    return (unsigned short)r;
}

// ---------------- CSR build ----------------

__global__ void hist_kernel(const int* __restrict__ dst, int* __restrict__ deg) {
    int i = blockIdx.x * blockDim.x + threadIdx.x;
    if (i < NE) atomicAdd(&deg[dst[i]], 1);
}

__global__ void scan_block(const int* __restrict__ deg, int* __restrict__ offs,
                           int* __restrict__ bsums) {
    __shared__ int s[256];
    int i = blockIdx.x * 256 + threadIdx.x;
    int v = (i < NN) ? deg[i] : 0;
    s[threadIdx.x] = v;
    __syncthreads();
    for (int off = 1; off < 256; off <<= 1) {
        int t = (threadIdx.x >= off) ? s[threadIdx.x - off] : 0;
        __syncthreads();
        s[threadIdx.x] += t;
        __syncthreads();
    }
    if (i < NN) offs[i + 1] = s[threadIdx.x];
    if (threadIdx.x == 255) bsums[blockIdx.x] = s[255];
}

__global__ void scan_sums(int* __restrict__ bsums, int nb) {
    if (blockIdx.x == 0 && threadIdx.x == 0) {
        int acc = 0;
        for (int i = 0; i < nb; ++i) { int v = bsums[i]; bsums[i] = acc; acc += v; }
    }
}

// offs[i+1] += bsums[block]; cursor[i+1] = final offs[i+1]; cursor[0]=0.
__global__ void add_offs(int* __restrict__ offs, const int* __restrict__ bsums,
                         int* __restrict__ cursor) {
    int i = blockIdx.x * blockDim.x + threadIdx.x;
    if (i == 0) { offs[0] = 0; cursor[0] = 0; }
    if (i < NN) {
        int o = offs[i + 1] + bsums[i >> 8];
        offs[i + 1] = o;
        if (i + 1 < NN) cursor[i + 1] = o;
    }
}

__global__ void scatter_edges(const int* __restrict__ src, const int* __restrict__ dst,
                              int* __restrict__ cursor, int* __restrict__ col) {
    int i = blockIdx.x * blockDim.x + threadIdx.x;
    if (i < NE) {
        int p = atomicAdd(&cursor[dst[i]], 1);
        col[p] = src[i];
    }
}

// ---------------- fp32 x -> bf16 self-columns of hcat ----------------
// hcat row layout: [mean 128 | self 128] bf16, stride 256.

__global__ __launch_bounds__(256) void convert_x(const float* __restrict__ x,
                                                 unsigned short* __restrict__ h) {
    int i = blockIdx.x * blockDim.x + threadIdx.x;   // handles 4 floats
    int idx = i * 4;
    if (idx >= NN * DH) return;
    int m = idx >> 7, j = idx & 127;
    float4 v = *(const float4*)(x + idx);
    unsigned int lo = (unsigned int)f2b(v.x) | ((unsigned int)f2b(v.y) << 16);
    unsigned int hi = (unsigned int)f2b(v.z) | ((unsigned int)f2b(v.w) << 16);
    unsigned int* p = (unsigned int*)(h + (size_t)m * 256 + 128 + j);
    p[0] = lo; p[1] = hi;
}

// ---------------- weight packing into B-fragment order ----------------
// Bp[ks][n][kk] = Wcat[ks*32+kk][n], Wcat = [Wl ; Wr] (256 x DC), bf16.

template <int DC>
__global__ __launch_bounds__(256) void pack_w(const float* __restrict__ Wl,
                                              const float* __restrict__ Wr,
                                              unsigned short* __restrict__ Bp) {
    int tid = blockIdx.x * blockDim.x + threadIdx.x;
    if (tid >= 256 * DC) return;
    int k = tid / DC, n = tid % DC;
    float v = (k < 128) ? Wl[k * DC + n] : Wr[(k - 128) * DC + n];
    int ks = k >> 5, kk = k & 31;
    Bp[((size_t)ks * DC + n) * 32 + kk] = f2b(v);
}

// ---------------- mean aggregation (bf16 rows): one wave per node -------
// reads self cols of h, writes mean cols of hm (same buffer ok).

__global__ __launch_bounds__(256) void agg_bf16(const unsigned short* __restrict__ h,
                                                const int* __restrict__ offs,
                                                const int* __restrict__ col,
                                                unsigned short* __restrict__ hm) {
    int gid = blockIdx.x * blockDim.x + threadIdx.x;
    int node = gid >> 6;
    int lane = gid & 63;
    if (node >= NN) return;
    int beg = offs[node], end = offs[node + 1];
    const unsigned short* base = h + 128 + lane * 2;
    float sx = 0.f, sy = 0.f;
    int e = beg;
    for (; e + 7 < end; e += 8) {
        unsigned int v0 = *(const unsigned int*)(base + (size_t)col[e]     * 256);
        unsigned int v1 = *(const unsigned int*)(base + (size_t)col[e + 1] * 256);
        unsigned int v2 = *(const unsigned int*)(base + (size_t)col[e + 2] * 256);
        unsigned int v3 = *(const unsigned int*)(base + (size_t)col[e + 3] * 256);
        unsigned int v4 = *(const unsigned int*)(base + (size_t)col[e + 4] * 256);
        unsigned int v5 = *(const unsigned int*)(base + (size_t)col[e + 5] * 256);
        unsigned int v6 = *(const unsigned int*)(base + (size_t)col[e + 6] * 256);
        unsigned int v7 = *(const unsigned int*)(base + (size_t)col[e + 7] * 256);
        float ax = __uint_as_float(v0 << 16) + __uint_as_float(v1 << 16)
                 + __uint_as_float(v2 << 16) + __uint_as_float(v3 << 16)
                 + __uint_as_float(v4 << 16) + __uint_as_float(v5 << 16)
                 + __uint_as_float(v6 << 16) + __uint_as_float(v7 << 16);
        float ay = __uint_as_float(v0 & 0xffff0000u) + __uint_as_float(v1 & 0xffff0000u)
                 + __uint_as_float(v2 & 0xffff0000u) + __uint_as_float(v3 & 0xffff0000u)
                 + __uint_as_float(v4 & 0xffff0000u) + __uint_as_float(v5 & 0xffff0000u)
                 + __uint_as_float(v6 & 0xffff0000u) + __uint_as_float(v7 & 0xffff0000u);
        sx += ax; sy += ay;
    }
    for (; e < end; ++e) {
        unsigned int v = *(const unsigned int*)(base + (size_t)col[e] * 256);
        sx += __uint_as_float(v << 16);
        sy += __uint_as_float(v & 0xffff0000u);
    }
    float inv = 1.0f / fmaxf((float)(end - beg), 1.0f);
    unsigned int o = (unsigned int)f2b(sx * inv) | ((unsigned int)f2b(sy * inv) << 16);
    *(unsigned int*)(hm + (size_t)node * 256 + lane * 2) = o;
}

// ---------------- MFMA dual-GEMM (+bias [+ReLU+LN]) ----------------
// A: hcat rows (bf16, stride 256, K=256). B: packed Bp. Out DC cols.
// Block = 256 threads = 4 waves; wave handles 16 rows (one M-tile).
// 625 blocks x 64 rows = 40000 exactly (no OOB).

template <int DC, bool LNRELU>
__global__ __launch_bounds__(256) void gemm_mfma(
    const unsigned short* __restrict__ A,
    const unsigned short* __restrict__ Bp,
    const float* __restrict__ bl,
    const float* __restrict__ g, const float* __restrict__ bln,
    unsigned short* __restrict__ outb,   // next hcat (self cols), LNRELU
    float* __restrict__ outf) {          // final fp32 out, !LNRELU
    constexpr int NT = DC / 16;
    const int tid = threadIdx.x;
    const int wave = tid >> 6, lane = tid & 63;
    const int quad = lane >> 4, l16 = lane & 15;
    const long row0 = (long)blockIdx.x * 64 + wave * 16;

    float4v acc[NT];
#pragma unroll
    for (int nt = 0; nt < NT; ++nt)
#pragma unroll
        for (int r = 0; r < 4; ++r) acc[nt][r] = 0.f;

    const unsigned short* ap = A + (row0 + l16) * 256 + quad * 8;

#pragma unroll
    for (int ks = 0; ks < 8; ++ks) {
        short8 a = *(const short8*)(ap + ks * 32);
        const unsigned short* bp = Bp + ((size_t)ks * DC + l16) * 32 + quad * 8;
#pragma unroll
        for (int nt = 0; nt < NT; ++nt) {
            short8 b = *(const short8*)(bp + nt * 16 * 32);
            acc[nt] = __builtin_amdgcn_mfma_f32_16x16x32_bf16(a, b, acc[nt], 0, 0, 0);
        }
    }

    float bias[NT];
#pragma unroll
    for (int nt = 0; nt < NT; ++nt) bias[nt] = bl[nt * 16 + l16];

    if (!LNRELU) {
#pragma unroll
        for (int r = 0; r < 4; ++r) {
            long row = row0 + quad * 4 + r;
#pragma unroll
            for (int nt = 0; nt < NT; ++nt)
                outf[row * DC + nt * 16 + l16] = acc[nt][r] + bias[nt];
        }
    } else {
        float gv[NT], bv[NT];
#pragma unroll
        for (int nt = 0; nt < NT; ++nt) { gv[nt] = g[nt * 16 + l16]; bv[nt] = bln[nt * 16 + l16]; }
#pragma unroll
        for (int r = 0; r < 4; ++r) {
            float v[NT];
            float s = 0.f, q = 0.f;
#pragma unroll
            for (int nt = 0; nt < NT; ++nt) {
                float t = fmaxf(acc[nt][r] + bias[nt], 0.f);
                v[nt] = t; s += t; q += t * t;
            }
            // reduce across the 16 lanes of this quad (row owners)
#pragma unroll
            for (int mask = 1; mask < 16; mask <<= 1) {
                s += __shfl_xor(s, mask, 64);
                q += __shfl_xor(q, mask, 64);
            }
            float mu = s * (1.f / 128.f);
            float rstd = rsqrtf(q * (1.f / 128.f) - mu * mu + LN_EPS);
            long row = row0 + quad * 4 + r;
            unsigned short* op = outb + row * 256 + 128 + l16;
#pragma unroll
            for (int nt = 0; nt < NT; ++nt)
                op[nt * 16] = f2b((v[nt] - mu) * rstd * gv[nt] + bv[nt]);
        }
    }
}

// ---------------- launch ----------------

static inline size_t alignup(size_t x) { return (x + 1023) & ~(size_t)1023; }

extern "C" void kernel_launch(void* const* d_in, const int* in_sizes, int n_in,
                              void* d_out, int out_size, void* d_ws, size_t ws_size,
                              hipStream_t stream) {
    const float* x   = (const float*)d_in[0];
    const int* ei    = (const int*)d_in[1];
    const float* Wl0 = (const float*)d_in[2];
    const float* bl0 = (const float*)d_in[3];
    const float* Wr0 = (const float*)d_in[4];
    const float* Wl1 = (const float*)d_in[5];
    const float* bl1 = (const float*)d_in[6];
    const float* Wr1 = (const float*)d_in[7];
    const float* Wl2 = (const float*)d_in[8];
    const float* bl2 = (const float*)d_in[9];
    const float* Wr2 = (const float*)d_in[10];
    const float* g0  = (const float*)d_in[11];
    const float* b0  = (const float*)d_in[12];
    const float* g1  = (const float*)d_in[13];
    const float* b1  = (const float*)d_in[14];

    const int* src = ei;
    const int* dst = ei + NE;

    char* p = (char*)d_ws;
    int* deg    = (int*)p; p += alignup((size_t)NN * 4);
    int* offs   = (int*)p; p += alignup((size_t)(NN + 1) * 4);
    int* bsums  = (int*)p; p += alignup(256 * 4);
    int* cursor = (int*)p; p += alignup((size_t)NN * 4);
    int* col    = (int*)p; p += alignup((size_t)NE * 4);
    unsigned short* hA = (unsigned short*)p; p += alignup((size_t)NN * 256 * 2);
    unsigned short* hB = (unsigned short*)p; p += alignup((size_t)NN * 256 * 2);
    unsigned short* W0p = (unsigned short*)p; p += alignup((size_t)256 * 128 * 2);
    unsigned short* W1p = (unsigned short*)p; p += alignup((size_t)256 * 128 * 2);
    unsigned short* W2p = (unsigned short*)p; p += alignup((size_t)256 * 64 * 2);
    float* outf = (float*)d_out;

    const int nbScan = (NN + 255) / 256;

    // ---- CSR build ----
    hipMemsetAsync(deg, 0, (size_t)NN * 4, stream);
    hist_kernel<<<(NE + 255) / 256, 256, 0, stream>>>(dst, deg);
    scan_block<<<nbScan, 256, 0, stream>>>(deg, offs, bsums);
    scan_sums<<<1, 64, 0, stream>>>(bsums, nbScan);
    add_offs<<<nbScan, 256, 0, stream>>>(offs, bsums, cursor);
    scatter_edges<<<(NE + 255) / 256, 256, 0, stream>>>(src, dst, cursor, col);

    // ---- weight packing + x conversion ----
    pack_w<128><<<128, 256, 0, stream>>>(Wl0, Wr0, W0p);
    pack_w<128><<<128, 256, 0, stream>>>(Wl1, Wr1, W1p);
    pack_w<64><<<64, 256, 0, stream>>>(Wl2, Wr2, W2p);
    convert_x<<<(NN * DH / 4 + 255) / 256, 256, 0, stream>>>(x, hA);

    const int aggBlocks = (NN * 64 + 255) / 256;   // 10000
    const int gemmBlocks = NN / 64;                // 625

    // ---- layer 0: hA = [agg(x)|x] -> hB self ----
    agg_bf16<<<aggBlocks, 256, 0, stream>>>(hA, offs, col, hA);
    gemm_mfma<128, true><<<gemmBlocks, 256, 0, stream>>>(
        hA, W0p, bl0, g0, b0, hB, nullptr);

    // ---- layer 1: hB -> hA self ----
    agg_bf16<<<aggBlocks, 256, 0, stream>>>(hB, offs, col, hB);
    gemm_mfma<128, true><<<gemmBlocks, 256, 0, stream>>>(
        hB, W1p, bl1, g1, b1, hA, nullptr);

    // ---- layer 2: hA -> d_out (fp32, 64 cols) ----
    agg_bf16<<<aggBlocks, 256, 0, stream>>>(hA, offs, col, hA);
    gemm_mfma<64, false><<<gemmBlocks, 256, 0, stream>>>(
        hA, W2p, bl2, nullptr, nullptr, nullptr, outf);
}